// Round 5
// baseline (167.710 us; speedup 1.0000x reference)
//
#include <hip/hip_runtime.h>
#include <math.h>

// Problem constants (from reference)
constexpr int   kS      = 7;
constexpr int   kNCls   = 20;
constexpr int   kB      = 16384;
constexpr int   kNCells = kB * kS * kS;   // 802,816
constexpr float kWCoord = 5.0f;
constexpr float kWNoobj = 0.5f;
constexpr float kEps    = 1e-6f;

constexpr int kBlocks  = 2048;            // 8 blocks/CU on 256 CUs
constexpr int kThreads = 256;

// ---------------------------------------------------------------------------
// Wave-64 + LDS block reduce. Returns full block sum on thread 0.
// ---------------------------------------------------------------------------
__device__ __forceinline__ float block_reduce(float v) {
    #pragma unroll
    for (int off = 32; off > 0; off >>= 1)
        v += __shfl_down(v, off, 64);
    __shared__ float smem[kThreads / 64];
    const int lane = threadIdx.x & 63;
    const int wv   = threadIdx.x >> 6;
    if (lane == 0) smem[wv] = v;
    __syncthreads();
    float t = 0.0f;
    if (threadIdx.x == 0) {
        #pragma unroll
        for (int i = 0; i < kThreads / 64; ++i) t += smem[i];
    }
    return t;
}

// ---------------------------------------------------------------------------
// IoU between two center-format boxes (matches reference _iou exactly).
// ---------------------------------------------------------------------------
__device__ __forceinline__ float iou_f(float ax, float ay, float aw, float ah,
                                       float gx, float gy, float gw, float gh) {
    const float ax1 = ax - aw * 0.5f, ax2 = ax + aw * 0.5f;
    const float ay1 = ay - ah * 0.5f, ay2 = ay + ah * 0.5f;
    const float gx1 = gx - gw * 0.5f, gx2 = gx + gw * 0.5f;
    const float gy1 = gy - gh * 0.5f, gy2 = gy + gh * 0.5f;
    const float iw = fmaxf(0.0f, fminf(ax2, gx2) - fmaxf(ax1, gx1));
    const float ih = fmaxf(0.0f, fminf(ay2, gy2) - fmaxf(ay1, gy1));
    const float inter = iw * ih;
    const float uni = aw * ah + gw * gh - inter;
    return inter / (uni + kEps);
}

// ---------------------------------------------------------------------------
// Fused kernel.
// Part A (noobj): 4 lanes per cell cooperatively read the 64B-aligned sector
//   containing that cell's ch20/21 pair (the pair never straddles a sector;
//   at most one pair per 64B window -> channel predicate e%30 in {20,21} is
//   exact). One wave-load = 16 consecutive cells = 16 contiguous 64B chunks:
//   ~15 lines/wave vs ~60 for the naive strided float2 (same fetched bytes).
// Part B: 64 labels per block on wave 0, one thread per label (coalesced 24B
//   label rows, 15x float2 cell gather).
// Each block atomicAdds its pre-scaled partial into d_out[0] (pre-zeroed by
// a 4-byte memset in the same graph).
// ---------------------------------------------------------------------------
__global__ void __launch_bounds__(kThreads)
fused_kernel(const float* __restrict__ out,
             const float* __restrict__ labels,
             int nl,
             float* __restrict__ result) {
    const int tid      = blockIdx.x * blockDim.x + threadIdx.x;
    const int nthreads = gridDim.x * blockDim.x;
    const int group    = tid >> 2;          // one cell per 4-lane group
    const int sub      = tid & 3;           // 16B slice within the 64B sector
    const int ngroups  = nthreads >> 2;
    const char* base   = reinterpret_cast<const char*>(out);

    float dsum = 0.0f;

    // --- Part A: noobj over all cells, sector-coalesced ---
    for (int c = group; c < kNCells; c += ngroups) {
        const size_t cellb  = (size_t)c * 120u + 80u;      // byte addr of ch20
        const size_t sector = cellb & ~(size_t)63;         // 64B-aligned sector
        const float4 v = *reinterpret_cast<const float4*>(base + sector + (sub << 4));
        const int e0 = (int)(sector >> 2) + (sub << 2);    // flat float index of v.x
        const int r  = e0 % 30;                            // channel of v.x
        const float vv[4] = {v.x, v.y, v.z, v.w};
        #pragma unroll
        for (int j = 0; j < 4; ++j) {
            int ch = r + j;
            ch = (ch >= 30) ? ch - 30 : ch;
            const bool hit = (ch == 20) || (ch == 21);
            dsum += hit ? vv[j] * vv[j] : 0.0f;
        }
    }
    float sum = kWNoobj * dsum;

    // --- Part B: per-label terms, 64 labels per block (wave 0) ---
    const int lpb  = (nl + gridDim.x - 1) / gridDim.x;     // 64
    const int lbase = blockIdx.x * lpb;
    for (int j = threadIdx.x; j < lpb; j += blockDim.x) {
        const int l = lbase + j;
        if (l >= nl) break;

        const float2* lab2 = reinterpret_cast<const float2*>(labels + (size_t)l * 6);
        const float2 l0 = lab2[0];
        const float2 l1 = lab2[1];
        const float2 l2 = lab2[2];
        const int   c  = (int)l0.y;
        const float gx = l1.x, gy = l1.y, gw = l2.x, gh = l2.y;

        const float rowf = floorf(gx * (float)kS);
        const float colf = floorf(gy * (float)kS);
        const int row = (int)rowf;
        const int col = (int)colf;
        const int b   = (int)l0.x;

        // gather the 30-float cell (byte offset 120*cell, always 8B aligned)
        const float* p = out + ((size_t)b * (kS * kS) + row * kS + col) * 30;
        const float2* p2 = reinterpret_cast<const float2*>(p);
        float pv[30];
        #pragma unroll
        for (int j2 = 0; j2 < 15; ++j2) {
            const float2 t = p2[j2];
            pv[2 * j2]     = t.x;
            pv[2 * j2 + 1] = t.y;
        }

        // class loss
        float cl = 0.0f;
        #pragma unroll
        for (int j2 = 0; j2 < kNCls; ++j2) {
            const float d = pv[j2] - ((j2 == c) ? 1.0f : 0.0f);
            cl += d * d;
        }

        // IoUs (global coords: (rowf + x)/S, exact division like reference)
        const float g1x = (rowf + pv[22]) / (float)kS;
        const float g1y = (colf + pv[23]) / (float)kS;
        const float g2x = (rowf + pv[26]) / (float)kS;
        const float g2y = (colf + pv[27]) / (float)kS;

        const float iou1 = iou_f(g1x, g1y, pv[24], pv[25], gx, gy, gw, gh);
        const float iou2 = iou_f(g2x, g2y, pv[28], pv[29], gx, gy, gw, gh);
        const bool use1 = (iou1 >= iou2);

        // coord loss
        const float gtx_cell = gx * (float)kS - rowf;
        const float gty_cell = gy * (float)kS - colf;
        const float px = use1 ? pv[22] : pv[26];
        const float py = use1 ? pv[23] : pv[27];
        const float pw = use1 ? pv[24] : pv[28];
        const float ph = use1 ? pv[25] : pv[29];
        const float dx = px - gtx_cell;
        const float dy = py - gty_cell;
        const float dw = sqrtf(pw + kEps) - sqrtf(gw + kEps);
        const float dh = sqrtf(ph + kEps) - sqrtf(gh + kEps);
        const float coord = kWCoord * (dx * dx + dy * dy + dw * dw + dh * dh);

        // conf loss (per-label part)
        const float cp = use1 ? pv[20] : pv[21];
        const float ct = use1 ? iou1 : iou2;
        const float conf = (cp - ct) * (cp - ct) - kWNoobj * cp * cp;

        sum += cl + coord + conf;
    }

    const float bsum = block_reduce(sum);
    if (threadIdx.x == 0)
        atomicAdd(result, bsum * (1.0f / (float)kB));
}

extern "C" void kernel_launch(void* const* d_in, const int* in_sizes, int n_in,
                              void* d_out, int out_size, void* d_ws, size_t ws_size,
                              hipStream_t stream) {
    const float* output = (const float*)d_in[0];   // (B, 7, 7, 30) fp32
    const float* labels = (const float*)d_in[1];   // (NL, 6) fp32
    float* out = (float*)d_out;

    const int nl = in_sizes[1] / 6;                // 131072

    // d_out is poisoned 0xAA before every timed launch — zero the scalar.
    hipMemsetAsync(out, 0, sizeof(float), stream);

    fused_kernel<<<kBlocks, kThreads, 0, stream>>>(output, labels, nl, out);
}

// Round 6
// 165.586 us; speedup vs baseline: 1.0128x; 1.0128x over previous
//
#include <hip/hip_runtime.h>
#include <math.h>

// Problem constants (from reference)
constexpr int   kS      = 7;
constexpr int   kNCls   = 20;
constexpr int   kB      = 16384;
constexpr int   kNCells = kB * kS * kS;          // 802,816
constexpr int   kNElems = kNCells * 30;          // 24,084,480 floats
constexpr float kWCoord = 5.0f;
constexpr float kWNoobj = 0.5f;
constexpr float kEps    = 1e-6f;

constexpr int kBlocks  = 2048;            // 8 blocks/CU on 256 CUs
constexpr int kThreads = 256;

// ---------------------------------------------------------------------------
// Wave-64 + LDS block reduce. Returns full block sum on thread 0.
// ---------------------------------------------------------------------------
__device__ __forceinline__ float block_reduce(float v) {
    #pragma unroll
    for (int off = 32; off > 0; off >>= 1)
        v += __shfl_down(v, off, 64);
    __shared__ float smem[kThreads / 64];
    const int lane = threadIdx.x & 63;
    const int wv   = threadIdx.x >> 6;
    if (lane == 0) smem[wv] = v;
    __syncthreads();
    float t = 0.0f;
    if (threadIdx.x == 0) {
        #pragma unroll
        for (int i = 0; i < kThreads / 64; ++i) t += smem[i];
    }
    return t;
}

// ---------------------------------------------------------------------------
// IoU between two center-format boxes (matches reference _iou exactly).
// ---------------------------------------------------------------------------
__device__ __forceinline__ float iou_f(float ax, float ay, float aw, float ah,
                                       float gx, float gy, float gw, float gh) {
    const float ax1 = ax - aw * 0.5f, ax2 = ax + aw * 0.5f;
    const float ay1 = ay - ah * 0.5f, ay2 = ay + ah * 0.5f;
    const float gx1 = gx - gw * 0.5f, gx2 = gx + gw * 0.5f;
    const float gy1 = gy - gh * 0.5f, gy2 = gy + gh * 0.5f;
    const float iw = fmaxf(0.0f, fminf(ax2, gx2) - fmaxf(ax1, gx1));
    const float ih = fmaxf(0.0f, fminf(ay2, gy2) - fmaxf(ay1, gy1));
    const float inter = iw * ih;
    const float uni = aw * ah + gw * gh - inter;
    return inter / (uni + kEps);
}

// ---------------------------------------------------------------------------
// Fused kernel.
// Part A (noobj): DENSE sequential float4 read of the ENTIRE output array.
//   R4/R5 proved sparse/strided patterns run at ~1.6 TB/s DRAM-effective
//   (every 128B line holds a needed pair, so DRAM moves ~96MB regardless);
//   sequential streaming runs at ~6 TB/s. Channel predicate (4i) mod 30 in
//   {20,21} costs ~12 VALU per 16B — far below the VALU ceiling.
// Part B: 64 labels per block on wave 0 (coalesced 24B rows, 15x float2 cell
//   gather).
// Each block atomicAdds its pre-scaled partial into d_out[0] (pre-zeroed by
// a 4-byte memset in the same graph).
// ---------------------------------------------------------------------------
__global__ void __launch_bounds__(kThreads)
fused_kernel(const float* __restrict__ out,
             const float* __restrict__ labels,
             int nl,
             float* __restrict__ result) {
    const int tid    = blockIdx.x * blockDim.x + threadIdx.x;
    const int stride = gridDim.x * blockDim.x;
    const float4* o4 = reinterpret_cast<const float4*>(out);
    const int n4     = kNElems / 4;          // 6,021,120 (divisible)

    float dsum = 0.0f;

    // --- Part A: dense sequential stream over the whole array ---
    for (int i = tid; i < n4; i += stride) {
        const float4 v = o4[i];
        const int ch0 = (i * 4) % 30;
        const float vv[4] = {v.x, v.y, v.z, v.w};
        #pragma unroll
        for (int j = 0; j < 4; ++j) {
            int ch = ch0 + j;
            ch = (ch >= 30) ? ch - 30 : ch;
            const bool hit = (ch == 20) || (ch == 21);
            dsum += hit ? vv[j] * vv[j] : 0.0f;
        }
    }
    float sum = kWNoobj * dsum;

    // --- Part B: per-label terms, 64 labels per block (wave 0) ---
    const int lpb   = (nl + gridDim.x - 1) / gridDim.x;   // 64
    const int lbase = blockIdx.x * lpb;
    for (int j = threadIdx.x; j < lpb; j += blockDim.x) {
        const int l = lbase + j;
        if (l >= nl) break;

        const float2* lab2 = reinterpret_cast<const float2*>(labels + (size_t)l * 6);
        const float2 l0 = lab2[0];
        const float2 l1 = lab2[1];
        const float2 l2 = lab2[2];
        const int   c  = (int)l0.y;
        const float gx = l1.x, gy = l1.y, gw = l2.x, gh = l2.y;

        const float rowf = floorf(gx * (float)kS);
        const float colf = floorf(gy * (float)kS);
        const int row = (int)rowf;
        const int col = (int)colf;
        const int b   = (int)l0.x;

        // gather the 30-float cell (byte offset 120*cell, always 8B aligned)
        const float* p = out + ((size_t)b * (kS * kS) + row * kS + col) * 30;
        const float2* p2 = reinterpret_cast<const float2*>(p);
        float pv[30];
        #pragma unroll
        for (int j2 = 0; j2 < 15; ++j2) {
            const float2 t = p2[j2];
            pv[2 * j2]     = t.x;
            pv[2 * j2 + 1] = t.y;
        }

        // class loss
        float cl = 0.0f;
        #pragma unroll
        for (int j2 = 0; j2 < kNCls; ++j2) {
            const float d = pv[j2] - ((j2 == c) ? 1.0f : 0.0f);
            cl += d * d;
        }

        // IoUs (global coords: (rowf + x)/S, exact division like reference)
        const float g1x = (rowf + pv[22]) / (float)kS;
        const float g1y = (colf + pv[23]) / (float)kS;
        const float g2x = (rowf + pv[26]) / (float)kS;
        const float g2y = (colf + pv[27]) / (float)kS;

        const float iou1 = iou_f(g1x, g1y, pv[24], pv[25], gx, gy, gw, gh);
        const float iou2 = iou_f(g2x, g2y, pv[28], pv[29], gx, gy, gw, gh);
        const bool use1 = (iou1 >= iou2);

        // coord loss
        const float gtx_cell = gx * (float)kS - rowf;
        const float gty_cell = gy * (float)kS - colf;
        const float px = use1 ? pv[22] : pv[26];
        const float py = use1 ? pv[23] : pv[27];
        const float pw = use1 ? pv[24] : pv[28];
        const float ph = use1 ? pv[25] : pv[29];
        const float dx = px - gtx_cell;
        const float dy = py - gty_cell;
        const float dw = sqrtf(pw + kEps) - sqrtf(gw + kEps);
        const float dh = sqrtf(ph + kEps) - sqrtf(gh + kEps);
        const float coord = kWCoord * (dx * dx + dy * dy + dw * dw + dh * dh);

        // conf loss (per-label part)
        const float cp = use1 ? pv[20] : pv[21];
        const float ct = use1 ? iou1 : iou2;
        const float conf = (cp - ct) * (cp - ct) - kWNoobj * cp * cp;

        sum += cl + coord + conf;
    }

    const float bsum = block_reduce(sum);
    if (threadIdx.x == 0)
        atomicAdd(result, bsum * (1.0f / (float)kB));
}

extern "C" void kernel_launch(void* const* d_in, const int* in_sizes, int n_in,
                              void* d_out, int out_size, void* d_ws, size_t ws_size,
                              hipStream_t stream) {
    const float* output = (const float*)d_in[0];   // (B, 7, 7, 30) fp32
    const float* labels = (const float*)d_in[1];   // (NL, 6) fp32
    float* out = (float*)d_out;

    const int nl = in_sizes[1] / 6;                // 131072

    // d_out is poisoned 0xAA before every timed launch — zero the scalar.
    hipMemsetAsync(out, 0, sizeof(float), stream);

    fused_kernel<<<kBlocks, kThreads, 0, stream>>>(output, labels, nl, out);
}

// Round 7
// 144.703 us; speedup vs baseline: 1.1590x; 1.1443x over previous
//
#include <hip/hip_runtime.h>
#include <math.h>

// Problem constants (from reference)
constexpr int   kS      = 7;
constexpr int   kNCls   = 20;
constexpr int   kB      = 16384;
constexpr int   kNCells = kB * kS * kS;          // 802,816
constexpr int   kNElems = kNCells * 30;          // 24,084,480 floats
constexpr float kWCoord = 5.0f;
constexpr float kWNoobj = 0.5f;
constexpr float kEps    = 1e-6f;

constexpr int kBlocks  = 2048;            // 8 blocks/CU on 256 CUs
constexpr int kThreads = 256;

// ---------------------------------------------------------------------------
// Wave-64 + LDS block reduce. Returns full block sum on thread 0.
// ---------------------------------------------------------------------------
__device__ __forceinline__ float block_reduce(float v) {
    #pragma unroll
    for (int off = 32; off > 0; off >>= 1)
        v += __shfl_down(v, off, 64);
    __shared__ float smem[kThreads / 64];
    const int lane = threadIdx.x & 63;
    const int wv   = threadIdx.x >> 6;
    if (lane == 0) smem[wv] = v;
    __syncthreads();
    float t = 0.0f;
    if (threadIdx.x == 0) {
        #pragma unroll
        for (int i = 0; i < kThreads / 64; ++i) t += smem[i];
    }
    return t;
}

// ---------------------------------------------------------------------------
// IoU between two center-format boxes (matches reference _iou exactly).
// ---------------------------------------------------------------------------
__device__ __forceinline__ float iou_f(float ax, float ay, float aw, float ah,
                                       float gx, float gy, float gw, float gh) {
    const float ax1 = ax - aw * 0.5f, ax2 = ax + aw * 0.5f;
    const float ay1 = ay - ah * 0.5f, ay2 = ay + ah * 0.5f;
    const float gx1 = gx - gw * 0.5f, gx2 = gx + gw * 0.5f;
    const float gy1 = gy - gh * 0.5f, gy2 = gy + gh * 0.5f;
    const float iw = fmaxf(0.0f, fminf(ax2, gx2) - fmaxf(ax1, gx1));
    const float ih = fmaxf(0.0f, fminf(ay2, gy2) - fmaxf(ay1, gy1));
    const float inter = iw * ih;
    const float uni = aw * ah + gw * gh - inter;
    return inter / (uni + kEps);
}

// ---------------------------------------------------------------------------
// Fused kernel.
// Part A (noobj): dense sequential float4 stream over the whole array
//   (largely L3-resident after the harness's d_in restore).
// Part B: 64 labels per block on wave 0 (coalesced 24B rows, 15x float2 cell
//   gather).
// Finish: per-block partial -> plain store to partials[blockIdx.x].
//   NO same-address atomics: R4/R5/R6 showed 2048 single-address atomicAdds
//   pin the kernel at a constant ~60us (serialized cross-XCD coherence ops).
// ---------------------------------------------------------------------------
__global__ void __launch_bounds__(kThreads)
fused_kernel(const float* __restrict__ out,
             const float* __restrict__ labels,
             int nl,
             float* __restrict__ partials) {
    const int tid    = blockIdx.x * blockDim.x + threadIdx.x;
    const int stride = gridDim.x * blockDim.x;
    const float4* o4 = reinterpret_cast<const float4*>(out);
    const int n4     = kNElems / 4;          // 6,021,120 (divisible)

    float dsum = 0.0f;

    // --- Part A: dense sequential stream over the whole array ---
    for (int i = tid; i < n4; i += stride) {
        const float4 v = o4[i];
        const int ch0 = (i * 4) % 30;
        const float vv[4] = {v.x, v.y, v.z, v.w};
        #pragma unroll
        for (int j = 0; j < 4; ++j) {
            int ch = ch0 + j;
            ch = (ch >= 30) ? ch - 30 : ch;
            const bool hit = (ch == 20) || (ch == 21);
            dsum += hit ? vv[j] * vv[j] : 0.0f;
        }
    }
    float sum = kWNoobj * dsum;

    // --- Part B: per-label terms, 64 labels per block (wave 0) ---
    const int lpb   = (nl + gridDim.x - 1) / gridDim.x;   // 64
    const int lbase = blockIdx.x * lpb;
    for (int j = threadIdx.x; j < lpb; j += blockDim.x) {
        const int l = lbase + j;
        if (l >= nl) break;

        const float2* lab2 = reinterpret_cast<const float2*>(labels + (size_t)l * 6);
        const float2 l0 = lab2[0];
        const float2 l1 = lab2[1];
        const float2 l2 = lab2[2];
        const int   c  = (int)l0.y;
        const float gx = l1.x, gy = l1.y, gw = l2.x, gh = l2.y;

        const float rowf = floorf(gx * (float)kS);
        const float colf = floorf(gy * (float)kS);
        const int row = (int)rowf;
        const int col = (int)colf;
        const int b   = (int)l0.x;

        // gather the 30-float cell (byte offset 120*cell, always 8B aligned)
        const float* p = out + ((size_t)b * (kS * kS) + row * kS + col) * 30;
        const float2* p2 = reinterpret_cast<const float2*>(p);
        float pv[30];
        #pragma unroll
        for (int j2 = 0; j2 < 15; ++j2) {
            const float2 t = p2[j2];
            pv[2 * j2]     = t.x;
            pv[2 * j2 + 1] = t.y;
        }

        // class loss
        float cl = 0.0f;
        #pragma unroll
        for (int j2 = 0; j2 < kNCls; ++j2) {
            const float d = pv[j2] - ((j2 == c) ? 1.0f : 0.0f);
            cl += d * d;
        }

        // IoUs (global coords: (rowf + x)/S, exact division like reference)
        const float g1x = (rowf + pv[22]) / (float)kS;
        const float g1y = (colf + pv[23]) / (float)kS;
        const float g2x = (rowf + pv[26]) / (float)kS;
        const float g2y = (colf + pv[27]) / (float)kS;

        const float iou1 = iou_f(g1x, g1y, pv[24], pv[25], gx, gy, gw, gh);
        const float iou2 = iou_f(g2x, g2y, pv[28], pv[29], gx, gy, gw, gh);
        const bool use1 = (iou1 >= iou2);

        // coord loss
        const float gtx_cell = gx * (float)kS - rowf;
        const float gty_cell = gy * (float)kS - colf;
        const float px = use1 ? pv[22] : pv[26];
        const float py = use1 ? pv[23] : pv[27];
        const float pw = use1 ? pv[24] : pv[28];
        const float ph = use1 ? pv[25] : pv[29];
        const float dx = px - gtx_cell;
        const float dy = py - gty_cell;
        const float dw = sqrtf(pw + kEps) - sqrtf(gw + kEps);
        const float dh = sqrtf(ph + kEps) - sqrtf(gh + kEps);
        const float coord = kWCoord * (dx * dx + dy * dy + dw * dw + dh * dh);

        // conf loss (per-label part)
        const float cp = use1 ? pv[20] : pv[21];
        const float ct = use1 ? iou1 : iou2;
        const float conf = (cp - ct) * (cp - ct) - kWNoobj * cp * cp;

        sum += cl + coord + conf;
    }

    const float bsum = block_reduce(sum);
    if (threadIdx.x == 0) partials[blockIdx.x] = bsum;
}

// ---------------------------------------------------------------------------
// Finalize: one block sums the 2048 per-block partials, divides by batch.
// ---------------------------------------------------------------------------
__global__ void __launch_bounds__(kThreads)
finalize_kernel(const float* __restrict__ partials, int n, float* __restrict__ out) {
    float s = 0.0f;
    for (int i = threadIdx.x; i < n; i += blockDim.x) s += partials[i];
    const float t = block_reduce(s);
    if (threadIdx.x == 0) out[0] = t * (1.0f / (float)kB);
}

extern "C" void kernel_launch(void* const* d_in, const int* in_sizes, int n_in,
                              void* d_out, int out_size, void* d_ws, size_t ws_size,
                              hipStream_t stream) {
    const float* output = (const float*)d_in[0];   // (B, 7, 7, 30) fp32
    const float* labels = (const float*)d_in[1];   // (NL, 6) fp32
    float* out = (float*)d_out;
    float* partials = (float*)d_ws;                // kBlocks floats, fully overwritten

    const int nl = in_sizes[1] / 6;                // 131072

    fused_kernel<<<kBlocks, kThreads, 0, stream>>>(output, labels, nl, partials);
    finalize_kernel<<<1, kThreads, 0, stream>>>(partials, kBlocks, out);
}